// Round 6
// baseline (132303.381 us; speedup 1.0000x reference)
//
#include <hip/hip_runtime.h>
#include <hip/hip_fp16.h>

#define BATCH 64
#define TSEQ  2048
#define FEAT  256
#define HID   256
#define G4    1024   // 4*HID

typedef _Float16 half2_t __attribute__((ext_vector_type(2)));
typedef _Float16 f16x8 __attribute__((ext_vector_type(8)));
typedef float    f32x4 __attribute__((ext_vector_type(4)));

__device__ __forceinline__ float sig_f(float x)  { return 1.f / (1.f + __expf(-x)); }
__device__ __forceinline__ float tanh_f(float x) { return 1.f - 2.f / (__expf(2.f * x) + 1.f); }

__device__ __forceinline__ unsigned int pack2(float a, float b) {
    half2_t h = { (_Float16)a, (_Float16)b };
    return __builtin_bit_cast(unsigned int, h);
}

__device__ __forceinline__ f16x8 u4_to_h8(uint4 v) {
    return __builtin_bit_cast(f16x8, v);
}

// ---------------- prep: WeightH fp32 [k][j] -> MFMA B-fragments fp16 ----------------
// lstm_rec thread tid (wave w=tid>>6, lane l=tid&63, g=l>>4, r=l&15) owns, for
// col-group cg in [0,4) and k-group kg in [0,8), the B-fragment of
// v_mfma_f32_16x16x32_f16 for cols n = w*64 + cg*16 + r, k in [32kg, 32kg+32).
// Fragment slot map (lane l, 4 dwords x 2 f16): .x.y = k = 32kg + 4g + {0..3},
// .z.w = k = 32kg + 16 + 4g + {0..3}; col = r. The A-fragment in lstm_rec is built
// with the SAME (g,dword)->k map, so any consistent k-permutation cancels in the
// MFMA dot product (A/B fragment k-maps are symmetric; only col=lane&15
// [m89-verified] must be right). WS[(cg*8+kg)*1024 + tid].
__global__ void wt_convert(const float* __restrict__ WH, uint4* __restrict__ WS) {
    int idx = blockIdx.x * 256 + threadIdx.x;   // 32768 total
    int f = idx >> 10;          // frag index: cg*8+kg
    int tid = idx & 1023;
    int w = tid >> 6;
    int l = tid & 63;
    int g = (l >> 4) & 3;
    int r = l & 15;
    int cg = f >> 3, kg = f & 7;
    int j = w * 64 + cg * 16 + r;
    int kb = kg * 32 + 4 * g;
    uint4 v;
    v.x = pack2(WH[(kb + 0) * G4 + j],  WH[(kb + 1) * G4 + j]);
    v.y = pack2(WH[(kb + 2) * G4 + j],  WH[(kb + 3) * G4 + j]);
    v.z = pack2(WH[(kb + 16) * G4 + j], WH[(kb + 17) * G4 + j]);
    v.w = pack2(WH[(kb + 18) * G4 + j], WH[(kb + 19) * G4 + j]);
    WS[(size_t)f * 1024 + tid] = v;
}

// ---------------- phase 1: xp = x @ Wx + bx + bh, stored fp16 (unchanged) ----------------
__global__ __launch_bounds__(256) void xproj_gemm(
    const float* __restrict__ X, const float* __restrict__ WX,
    const float* __restrict__ BX, const float* __restrict__ BH,
    _Float16* __restrict__ XP)
{
    __shared__ float As[64][17];
    __shared__ float Bs[16][68];

    const int tid = threadIdx.x;
    const int tx = tid & 15;
    const int ty = tid >> 4;
    const int rowBase = blockIdx.y * 64;
    const int colBase = blockIdx.x * 64;

    const int ea = tid * 4;
    const int ar = ea >> 4, ac = ea & 15;
    const int br = ea >> 6, bc = ea & 63;

    float acc[4][4] = {};

    for (int kt = 0; kt < FEAT; kt += 16) {
        float4 av = *(const float4*)(X  + (size_t)(rowBase + ar) * FEAT + kt + ac);
        float4 bv = *(const float4*)(WX + (size_t)(kt + br) * G4 + colBase + bc);
        As[ar][ac + 0] = av.x; As[ar][ac + 1] = av.y;
        As[ar][ac + 2] = av.z; As[ar][ac + 3] = av.w;
        *(float4*)&Bs[br][bc] = bv;
        __syncthreads();
        #pragma unroll
        for (int kk = 0; kk < 16; ++kk) {
            float4 b = *(const float4*)&Bs[kk][tx * 4];
            float a0 = As[ty * 4 + 0][kk];
            float a1 = As[ty * 4 + 1][kk];
            float a2 = As[ty * 4 + 2][kk];
            float a3 = As[ty * 4 + 3][kk];
            acc[0][0] = fmaf(a0, b.x, acc[0][0]); acc[0][1] = fmaf(a0, b.y, acc[0][1]);
            acc[0][2] = fmaf(a0, b.z, acc[0][2]); acc[0][3] = fmaf(a0, b.w, acc[0][3]);
            acc[1][0] = fmaf(a1, b.x, acc[1][0]); acc[1][1] = fmaf(a1, b.y, acc[1][1]);
            acc[1][2] = fmaf(a1, b.z, acc[1][2]); acc[1][3] = fmaf(a1, b.w, acc[1][3]);
            acc[2][0] = fmaf(a2, b.x, acc[2][0]); acc[2][1] = fmaf(a2, b.y, acc[2][1]);
            acc[2][2] = fmaf(a2, b.z, acc[2][2]); acc[2][3] = fmaf(a2, b.w, acc[2][3]);
            acc[3][0] = fmaf(a3, b.x, acc[3][0]); acc[3][1] = fmaf(a3, b.y, acc[3][1]);
            acc[3][2] = fmaf(a3, b.z, acc[3][2]); acc[3][3] = fmaf(a3, b.w, acc[3][3]);
        }
        __syncthreads();
    }

    const int n0 = colBase + tx * 4;
    float4 bxv = *(const float4*)(BX + n0);
    float4 bhv = *(const float4*)(BH + n0);
    float bb0 = bxv.x + bhv.x, bb1 = bxv.y + bhv.y;
    float bb2 = bxv.z + bhv.z, bb3 = bxv.w + bhv.w;

    #pragma unroll
    for (int i = 0; i < 4; ++i) {
        int row = rowBase + ty * 4 + i;
        _Float16* p = XP + (size_t)row * G4 + n0;
        half2_t p01 = { (_Float16)(acc[i][0] + bb0), (_Float16)(acc[i][1] + bb1) };
        half2_t p23 = { (_Float16)(acc[i][2] + bb2), (_Float16)(acc[i][3] + bb3) };
        *(half2_t*)(p + 0) = p01;
        *(half2_t*)(p + 2) = p23;
    }
}

// ---------------- phase 2: recurrence on the MATRIX pipe ----------------
// R0-R4 fed h@Wh through the VALU (2 MAC/inst); MfmaUtil was 0.0 every round.
// R5 (this design) produced NaN: post-mortem attributes it to the unproven
// empty-asm tied vector-"a" transfer leaving wb as UNINITIALIZED AGPRs (all
// memory paths audited in-bounds; layout errors give finite-wrong, not NaN).
// This round uses only proven ingredients:
//   - B-fragments loaded as plain uint4 values (defined data, no exotic asm);
//   - residency enforced by a per-iteration SCALAR-component keep-alive chain
//     asm("" : "+a"(wb[f].x..w)) — struct-member "a"-class lvalues are R3-proven;
//     the loop-carried asm chain makes remat/reload illegal, and at 1024 thr
//     (4 waves/SIMD, 512-reg budget) there is zero pressure to split the quads.
// Per wave: 64 gate cols = 4 col-groups x 8 K-accumulating MFMAs (K=256).
// A-fragment = h broadcast from 512 B LDS: all 16 A-rows equal h (af depends only
// on g), so D[*][n] = gates[n]; read row 0 = lanes 0-15, dword .x (C/D col=lane&15,
// row=(lane>>4)*4+reg, m89-verified, dtype-independent). MFMA reduces K internally:
// no DPP, no dependent fdot2 chains, zero per-step weight VALU cost.
__global__ __launch_bounds__(1024, 1) void lstm_rec(
    const _Float16* __restrict__ XP, const uint4* __restrict__ WS,
    float* __restrict__ OUT)
{
    __shared__ float g_sh[G4];                            // 4 KB gates
    __shared__ __align__(16) _Float16 hs[HID];            // 512 B, k-linear h

    const int tid = threadIdx.x;
    const int b = blockIdx.x;
    const int w = tid >> 6;
    const int l = tid & 63;
    const int g = (l >> 4) & 3;

    // one-time: plain loads of all 32 B-fragments (128 regs target: AGPR)
    uint4 wb[32];
    #pragma unroll
    for (int f = 0; f < 32; ++f)
        wb[f] = WS[(size_t)f * 1024 + tid];

    if (tid < 128) ((unsigned*)hs)[tid] = 0;              // h(-1) = 0
    float cst = 0.f, hlast = 0.f;
    const _Float16* xpb = XP + (size_t)b * TSEQ * G4;
    float* outb = OUT + (size_t)b * TSEQ * HID;

    // xp for t=0 (later steps prefetched one step ahead)
    float xv0 = 0.f, xv1 = 0.f, xv2 = 0.f, xv3 = 0.f;
    if (tid < 256) {
        xv0 = (float)xpb[tid];       xv1 = (float)xpb[tid + 256];
        xv2 = (float)xpb[tid + 512]; xv3 = (float)xpb[tid + 768];
    }
    __syncthreads();

    #pragma unroll 1
    for (int t = 0; t < TSEQ; ++t) {
        // keep-alive chain: pins wb in AGPRs, forbids remat (reload would discard
        // the asm's possible redefinition). Emits zero instructions in steady state.
        #pragma unroll
        for (int f = 0; f < 32; ++f)
            asm("" : "+a"(wb[f].x), "+a"(wb[f].y), "+a"(wb[f].z), "+a"(wb[f].w));

        // A-fragments: h slices, same (g,dword)->k map as wt_convert.
        // kg: .x.y = h[32kg+4g .. +3] (bytes 64kg+8g), .z.w = h[32kg+16+4g .. +3]
        uint4 af[8];
        const char* hb = (const char*)hs + (g << 3);
        #pragma unroll
        for (int kg = 0; kg < 8; ++kg) {
            uint2 lo = *(const uint2*)(hb + (kg << 6));
            uint2 hi = *(const uint2*)(hb + (kg << 6) + 32);
            af[kg] = make_uint4(lo.x, lo.y, hi.x, hi.y);
        }

        // next-step xp prefetch (one wave per SIMD): hides XP latency under MFMAs
        float xn0 = 0.f, xn1 = 0.f, xn2 = 0.f, xn3 = 0.f;
        if (tid < 256) {
            int tn = (t + 1 < TSEQ) ? (t + 1) : t;
            const _Float16* xq = xpb + (size_t)tn * G4;
            xn0 = (float)xq[tid];       xn1 = (float)xq[tid + 256];
            xn2 = (float)xq[tid + 512]; xn3 = (float)xq[tid + 768];
        }

        // 4 col-group chains x 8 K-accumulating MFMAs
        #pragma unroll
        for (int cg = 0; cg < 4; ++cg) {
            f32x4 acc = {0.f, 0.f, 0.f, 0.f};
            #pragma unroll
            for (int kg = 0; kg < 8; ++kg)
                acc = __builtin_amdgcn_mfma_f32_16x16x32_f16(
                    u4_to_h8(af[kg]), u4_to_h8(wb[cg * 8 + kg]), acc, 0, 0, 0);
            // D row 0 = lanes 0-15, dword .x; col = lane&15
            if (l < 16) g_sh[w * 64 + cg * 16 + l] = acc[0];
        }
        __syncthreads();                                  // gates ready

        if (tid < 256) {
            float gi = sig_f(g_sh[tid] + xv0);
            float gf = sig_f(g_sh[tid + 256] + xv1);
            float gg = tanh_f(g_sh[tid + 512] + xv2);
            float go = sig_f(g_sh[tid + 768] + xv3);
            cst = gf * cst + gi * gg;
            float h = go * tanh_f(cst);
            outb[(size_t)t * HID + tid] = h;
            hlast = h;
            hs[tid] = (_Float16)h;
        }
        xv0 = xn0; xv1 = xn1; xv2 = xn2; xv3 = xn3;
        __syncthreads();                                  // h visible for next step
    }

    if (tid < 256)
        OUT[(size_t)BATCH * TSEQ * HID + (size_t)b * HID + tid] = hlast;
}

extern "C" void kernel_launch(void* const* d_in, const int* in_sizes, int n_in,
                              void* d_out, int out_size, void* d_ws, size_t ws_size,
                              hipStream_t stream) {
    const float* x  = (const float*)d_in[0];
    const float* wx = (const float*)d_in[1];
    const float* wh = (const float*)d_in[2];
    const float* bx = (const float*)d_in[3];
    const float* bh = (const float*)d_in[4];
    float* out = (float*)d_out;

    // workspace: [xp fp16: 256 MB][WS: 32768 uint4 = 512 KB]
    _Float16* xp = (_Float16*)d_ws;
    uint4* ws = (uint4*)((char*)d_ws + (size_t)BATCH * TSEQ * G4 * sizeof(_Float16));

    hipLaunchKernelGGL(wt_convert, dim3(128), dim3(256), 0, stream, wh, ws);
    hipLaunchKernelGGL(xproj_gemm, dim3(G4 / 64, (BATCH * TSEQ) / 64), dim3(256), 0, stream,
                       x, wx, bx, bh, xp);
    hipLaunchKernelGGL(lstm_rec, dim3(BATCH), dim3(1024), 0, stream, xp, ws, out);
}

// Round 7
// 45997.128 us; speedup vs baseline: 2.8763x; 2.8763x over previous
//
#include <hip/hip_runtime.h>
#include <hip/hip_fp16.h>

#define BATCH 64
#define TSEQ  2048
#define FEAT  256
#define HID   256
#define G4    1024   // 4*HID

typedef _Float16 half2_t __attribute__((ext_vector_type(2)));
typedef _Float16 f16x8 __attribute__((ext_vector_type(8)));
typedef float    f32x4 __attribute__((ext_vector_type(4)));

__device__ __forceinline__ float sig_f(float x)  { return 1.f / (1.f + __expf(-x)); }
__device__ __forceinline__ float tanh_f(float x) { return 1.f - 2.f / (__expf(2.f * x) + 1.f); }

__device__ __forceinline__ unsigned int pack2(float a, float b) {
    half2_t h = { (_Float16)a, (_Float16)b };
    return __builtin_bit_cast(unsigned int, h);
}

__device__ __forceinline__ f16x8 u4_to_h8(uint4 v) {
    return __builtin_bit_cast(f16x8, v);
}

// ---------------- prep: WeightH fp32 [k][j] -> MFMA B-fragments fp16 ----------------
// lstm_rec thread tid (wave w=tid>>6, lane l=tid&63, g=(l>>4)&3, r=l&15) owns, for
// col-group cg in [0,8) and k-group kg in [0,8), the B-fragment of
// v_mfma_f32_16x16x32_f16 for cols n = w*128 + cg*16 + r, k in [32kg, 32kg+32).
// Fragment slot map (validated end-to-end in R6, absmax 4.9e-4): dwords .x.y =
// k = 32kg + 4g + {0..3}, .z.w = k = 32kg + 16 + 4g + {0..3}; col = r. The
// A-fragment in lstm_rec uses the SAME (g,dword)->k map, so any consistent
// k-permutation cancels; only col=lane&15 (m89-verified) must be right.
// WS[(cg*8+kg)*512 + tid]; 64 frags x 512 thr = 512 KB.
__global__ void wt_convert(const float* __restrict__ WH, uint4* __restrict__ WS) {
    int idx = blockIdx.x * 256 + threadIdx.x;   // 32768 total
    int f = idx >> 9;           // frag index: cg*8+kg, 0..63
    int tid = idx & 511;
    int w = tid >> 6;
    int l = tid & 63;
    int g = (l >> 4) & 3;
    int r = l & 15;
    int cg = f >> 3, kg = f & 7;
    int j = w * 128 + cg * 16 + r;
    int kb = kg * 32 + 4 * g;
    uint4 v;
    v.x = pack2(WH[(kb + 0) * G4 + j],  WH[(kb + 1) * G4 + j]);
    v.y = pack2(WH[(kb + 2) * G4 + j],  WH[(kb + 3) * G4 + j]);
    v.z = pack2(WH[(kb + 16) * G4 + j], WH[(kb + 17) * G4 + j]);
    v.w = pack2(WH[(kb + 18) * G4 + j], WH[(kb + 19) * G4 + j]);
    WS[(size_t)f * 512 + tid] = v;
}

// ---------------- phase 1: xp = x @ Wx + bx + bh, stored fp16 (unchanged) ----------------
__global__ __launch_bounds__(256) void xproj_gemm(
    const float* __restrict__ X, const float* __restrict__ WX,
    const float* __restrict__ BX, const float* __restrict__ BH,
    _Float16* __restrict__ XP)
{
    __shared__ float As[64][17];
    __shared__ float Bs[16][68];

    const int tid = threadIdx.x;
    const int tx = tid & 15;
    const int ty = tid >> 4;
    const int rowBase = blockIdx.y * 64;
    const int colBase = blockIdx.x * 64;

    const int ea = tid * 4;
    const int ar = ea >> 4, ac = ea & 15;
    const int br = ea >> 6, bc = ea & 63;

    float acc[4][4] = {};

    for (int kt = 0; kt < FEAT; kt += 16) {
        float4 av = *(const float4*)(X  + (size_t)(rowBase + ar) * FEAT + kt + ac);
        float4 bv = *(const float4*)(WX + (size_t)(kt + br) * G4 + colBase + bc);
        As[ar][ac + 0] = av.x; As[ar][ac + 1] = av.y;
        As[ar][ac + 2] = av.z; As[ar][ac + 3] = av.w;
        *(float4*)&Bs[br][bc] = bv;
        __syncthreads();
        #pragma unroll
        for (int kk = 0; kk < 16; ++kk) {
            float4 b = *(const float4*)&Bs[kk][tx * 4];
            float a0 = As[ty * 4 + 0][kk];
            float a1 = As[ty * 4 + 1][kk];
            float a2 = As[ty * 4 + 2][kk];
            float a3 = As[ty * 4 + 3][kk];
            acc[0][0] = fmaf(a0, b.x, acc[0][0]); acc[0][1] = fmaf(a0, b.y, acc[0][1]);
            acc[0][2] = fmaf(a0, b.z, acc[0][2]); acc[0][3] = fmaf(a0, b.w, acc[0][3]);
            acc[1][0] = fmaf(a1, b.x, acc[1][0]); acc[1][1] = fmaf(a1, b.y, acc[1][1]);
            acc[1][2] = fmaf(a1, b.z, acc[1][2]); acc[1][3] = fmaf(a1, b.w, acc[1][3]);
            acc[2][0] = fmaf(a2, b.x, acc[2][0]); acc[2][1] = fmaf(a2, b.y, acc[2][1]);
            acc[2][2] = fmaf(a2, b.z, acc[2][2]); acc[2][3] = fmaf(a2, b.w, acc[2][3]);
            acc[3][0] = fmaf(a3, b.x, acc[3][0]); acc[3][1] = fmaf(a3, b.y, acc[3][1]);
            acc[3][2] = fmaf(a3, b.z, acc[3][2]); acc[3][3] = fmaf(a3, b.w, acc[3][3]);
        }
        __syncthreads();
    }

    const int n0 = colBase + tx * 4;
    float4 bxv = *(const float4*)(BX + n0);
    float4 bhv = *(const float4*)(BH + n0);
    float bb0 = bxv.x + bhv.x, bb1 = bxv.y + bhv.y;
    float bb2 = bxv.z + bhv.z, bb3 = bxv.w + bhv.w;

    #pragma unroll
    for (int i = 0; i < 4; ++i) {
        int row = rowBase + ty * 4 + i;
        _Float16* p = XP + (size_t)row * G4 + n0;
        half2_t p01 = { (_Float16)(acc[i][0] + bb0), (_Float16)(acc[i][1] + bb1) };
        half2_t p23 = { (_Float16)(acc[i][2] + bb2), (_Float16)(acc[i][3] + bb3) };
        *(half2_t*)(p + 0) = p01;
        *(half2_t*)(p + 2) = p23;
    }
}

// ---------------- phase 2: recurrence on the MATRIX pipe (512-thread re-shape) ----------------
// R6 validated the MFMA numerics but ran at 1024 thr = 128-reg/thread budget, so
// the 128 weight-AGPRs could NOT be resident: FETCH_SIZE showed 68 GB of per-step
// weight re-fetch. R3 empirically proved 160 AGPRs + 124 VGPRs persist at 512 thr
// under __launch_bounds__(512,2). This kernel re-shapes R6 into that envelope:
//   512 threads, 8 waves, wave w owns 128 cols = 8 col-groups; 64 B-frags/thread:
//     cg 0-4 (40 frags, 160 AGPRs): resident; MFMA reads A/B from AGPR natively
//       on gfx950 -> ZERO per-step VALU cost for these weights.
//     cg 5-6 (16 frags): LDS, 128 KB, conflict-free b128 (DS pipe, parallel).
//     cg 7   (8 frags): streamed from L2 (64 KB/step), issued at step top,
//       consumed last; opaque base defeats LICM (R3-proven pattern).
// A-frag = h broadcast from 512 B LDS (R6-validated map); D row 0 = lanes 0-15,
// dword .x (m89-verified). Per step per CU: 512 MFMAs (~2500 cyc matrix pipe),
// DS ~1500 cyc hidden, elementwise tail ~500.
__global__ __launch_bounds__(512, 2) void lstm_rec(
    const _Float16* __restrict__ XP, const uint4* __restrict__ WS,
    float* __restrict__ OUT)
{
    __shared__ uint4 LW[16 * 512];                        // cg 5-6 weights, 128 KB
    __shared__ float g_sh[G4];                            // 4 KB gates
    __shared__ __align__(16) _Float16 hs[HID];            // 512 B, k-linear h

    const int tid = threadIdx.x;
    const int b = blockIdx.x;
    const int w = tid >> 6;
    const int l = tid & 63;
    const int g = (l >> 4) & 3;

    // one-time: cg 0-4 fragments into registers (target: 160 AGPRs)
    uint4 wb[40];
    #pragma unroll
    for (int f = 0; f < 40; ++f)
        wb[f] = WS[(size_t)f * 512 + tid];

    // one-time: cg 5-6 fragments into LDS (SoA, 16 B stride, conflict-free)
    #pragma unroll
    for (int i = 0; i < 16; ++i)
        LW[i * 512 + tid] = WS[(size_t)(40 + i) * 512 + tid];

    if (tid < 128) ((unsigned*)hs)[tid] = 0;              // h(-1) = 0
    float cst = 0.f, hlast = 0.f;
    const _Float16* xpb = XP + (size_t)b * TSEQ * G4;
    float* outb = OUT + (size_t)b * TSEQ * HID;

    // xp for t=0 (later steps prefetched one step ahead)
    float xv0 = 0.f, xv1 = 0.f, xv2 = 0.f, xv3 = 0.f;
    if (tid < 256) {
        xv0 = (float)xpb[tid];       xv1 = (float)xpb[tid + 256];
        xv2 = (float)xpb[tid + 512]; xv3 = (float)xpb[tid + 768];
    }
    __syncthreads();

    #pragma unroll 1
    for (int t = 0; t < TSEQ; ++t) {
        // keep-alive chain: pins wb in the "a" class each iteration; with the
        // 512-thread budget (R3: 160 AGPR + 124 VGPR persistent) the allocator
        // keeps them resident instead of reloading (R6's 1024-thr failure mode).
        #pragma unroll
        for (int f = 0; f < 40; ++f)
            asm("" : "+a"(wb[f].x), "+a"(wb[f].y), "+a"(wb[f].z), "+a"(wb[f].w));

        // A-fragments: h slices, same (g,dword)->k map as wt_convert (R6-validated)
        uint4 af[8];
        const char* hb = (const char*)hs + (g << 3);
        #pragma unroll
        for (int kg = 0; kg < 8; ++kg) {
            uint2 lo = *(const uint2*)(hb + (kg << 6));
            uint2 hi = *(const uint2*)(hb + (kg << 6) + 32);
            af[kg] = make_uint4(lo.x, lo.y, hi.x, hi.y);
        }

        // stream cg 7: issue early (opaque base, loop-variant), consume last
        uintptr_t stb_i = (uintptr_t)WS;
        asm volatile("" : "+s"(stb_i));
        const uint4* stb = (const uint4*)stb_i;
        uint4 pf[8];
        #pragma unroll
        for (int kg = 0; kg < 8; ++kg)
            pf[kg] = stb[(size_t)(56 + kg) * 512 + tid];

        // next-step xp prefetch: hides XP (HBM) latency under the MFMAs
        float xn0 = 0.f, xn1 = 0.f, xn2 = 0.f, xn3 = 0.f;
        if (tid < 256) {
            int tn = (t + 1 < TSEQ) ? (t + 1) : t;
            const _Float16* xq = xpb + (size_t)tn * G4;
            xn0 = (float)xq[tid];       xn1 = (float)xq[tid + 256];
            xn2 = (float)xq[tid + 512]; xn3 = (float)xq[tid + 768];
        }

        // cg 0-4: AGPR-resident B
        #pragma unroll
        for (int cg = 0; cg < 5; ++cg) {
            f32x4 acc = {0.f, 0.f, 0.f, 0.f};
            #pragma unroll
            for (int kg = 0; kg < 8; ++kg)
                acc = __builtin_amdgcn_mfma_f32_16x16x32_f16(
                    u4_to_h8(af[kg]), u4_to_h8(wb[cg * 8 + kg]), acc, 0, 0, 0);
            if (l < 16) g_sh[w * 128 + cg * 16 + l] = acc[0];
        }
        // cg 5-6: LDS B
        #pragma unroll
        for (int cc = 0; cc < 2; ++cc) {
            f32x4 acc = {0.f, 0.f, 0.f, 0.f};
            #pragma unroll
            for (int kg = 0; kg < 8; ++kg) {
                uint4 lv = LW[(cc * 8 + kg) * 512 + tid];
                acc = __builtin_amdgcn_mfma_f32_16x16x32_f16(
                    u4_to_h8(af[kg]), u4_to_h8(lv), acc, 0, 0, 0);
            }
            if (l < 16) g_sh[w * 128 + (5 + cc) * 16 + l] = acc[0];
        }
        // cg 7: streamed B
        {
            f32x4 acc = {0.f, 0.f, 0.f, 0.f};
            #pragma unroll
            for (int kg = 0; kg < 8; ++kg)
                acc = __builtin_amdgcn_mfma_f32_16x16x32_f16(
                    u4_to_h8(af[kg]), u4_to_h8(pf[kg]), acc, 0, 0, 0);
            if (l < 16) g_sh[w * 128 + 7 * 16 + l] = acc[0];
        }
        __syncthreads();                                  // gates ready

        if (tid < 256) {
            float gi = sig_f(g_sh[tid] + xv0);
            float gf = sig_f(g_sh[tid + 256] + xv1);
            float gg = tanh_f(g_sh[tid + 512] + xv2);
            float go = sig_f(g_sh[tid + 768] + xv3);
            cst = gf * cst + gi * gg;
            float h = go * tanh_f(cst);
            outb[(size_t)t * HID + tid] = h;
            hlast = h;
            hs[tid] = (_Float16)h;
        }
        xv0 = xn0; xv1 = xn1; xv2 = xn2; xv3 = xn3;
        __syncthreads();                                  // h visible for next step
    }

    if (tid < 256)
        OUT[(size_t)BATCH * TSEQ * HID + (size_t)b * HID + tid] = hlast;
}

extern "C" void kernel_launch(void* const* d_in, const int* in_sizes, int n_in,
                              void* d_out, int out_size, void* d_ws, size_t ws_size,
                              hipStream_t stream) {
    const float* x  = (const float*)d_in[0];
    const float* wx = (const float*)d_in[1];
    const float* wh = (const float*)d_in[2];
    const float* bx = (const float*)d_in[3];
    const float* bh = (const float*)d_in[4];
    float* out = (float*)d_out;

    // workspace: [xp fp16: 256 MB][WS: 32768 uint4 = 512 KB]
    _Float16* xp = (_Float16*)d_ws;
    uint4* ws = (uint4*)((char*)d_ws + (size_t)BATCH * TSEQ * G4 * sizeof(_Float16));

    hipLaunchKernelGGL(wt_convert, dim3(128), dim3(256), 0, stream, wh, ws);
    hipLaunchKernelGGL(xproj_gemm, dim3(G4 / 64, (BATCH * TSEQ) / 64), dim3(256), 0, stream,
                       x, wx, bx, bh, xp);
    hipLaunchKernelGGL(lstm_rec, dim3(BATCH), dim3(512), 0, stream, xp, ws, out);
}